// Round 6
// baseline (981.848 us; speedup 1.0000x reference)
//
#include <hip/hip_runtime.h>
#include <hip/hip_bf16.h>
#include <stdint.h>

#define MDIM 4096
#define KDIM 4096
#define NDIM 11008
#define NT   (KDIM / 32)   // 128 k-steps

typedef __bf16 bf16x8 __attribute__((ext_vector_type(8)));
typedef float  f32x4  __attribute__((ext_vector_type(4)));

// 256x256 tile, BK=32, 512 threads = 8 waves (2m x 4n); each wave owns
// 128x64 via 8x4 mfma_f32_16x16x32_bf16 fragments (32 MFMA per k-step).
// Round-6 change: m201-style 4-PHASE schedule inside each k-step. Each
// phase: {ds_reads for one C-quadrant + share of staging -> s_barrier ->
// lgkmcnt(0) -> setprio(1) 8 MFMA setprio(0) -> s_barrier}. The dual
// barrier phase-locks the 8 waves so one wave's LDS burst runs under the
// other wave's MFMA cluster (LDS pipe ~1540 cy/step and MFMA ~1240 cy/step
// must co-run, not alternate). Global loads issued at step kt are consumed
// at step kt+1 (T14 full-step latency cover) and stay IN FLIGHT across all
// barriers (raw s_barrier, lgkm drain only -- no vmcnt(0)).
// LDS (both sA, sB): rows of 32 bf16 (4x 16B chunks) in 2-row 128B windows,
// slot(row,c) = ((row&1)*4 + c) ^ ((row>>1)&7)  -- measured conflict-free
// (rounds 3-5: SQ_LDS_BANK_CONFLICT == 0).
// Fragment contracts (harness-verified):
//   A operand: lane(fr,fq) holds A[m=16i+fr][k=fq*8+e]
//   B operand: lane(fr,fq) holds B[k=fq*8+e][n=16j+fr]
//   C/D:       col = lane&15, row = (lane>>4)*4 + r
__global__ __launch_bounds__(512) void int4_gemm_mfma(
    const float* __restrict__ A, const int* __restrict__ Q,
    const float* __restrict__ S, const int* __restrict__ Z,
    const float* __restrict__ bias, float* __restrict__ out)
{
    __shared__ __bf16 sA[2][256 * 32];   // 2 x 16KB
    __shared__ __bf16 sB[2][256 * 32];   // 2 x 16KB  ([n][k])

    auto SW = [](int row, int c) -> int {
        return ((row >> 1) << 7) + (((((row & 1) << 2) | c) ^ ((row >> 1) & 7)) << 4);
    };

    // ---- XCD-chunked swizzle, bm fastest ----
    const int nbm = MDIM / 256;                      // 16
    const int nwg = (MDIM / 256) * (NDIM / 256);     // 688 (divisible by 8)
    const int xcd = blockIdx.x & 7;
    const int wg  = xcd * (nwg >> 3) + (blockIdx.x >> 3);
    const int bm  = wg % nbm;
    const int bn  = wg / nbm;
    const int m0 = bm * 256, n0 = bn * 256;

    const int t    = threadIdx.x;
    const int lane = t & 63;
    const int wave = t >> 6;
    const int wm   = (wave >> 2) * 128;  // wave tile: 128m x 64n
    const int wn   = (wave & 3) * 64;
    const int fr   = lane & 15;
    const int fq   = lane >> 4;          // k-octet

    // ---- staging maps ----
    const int arow = t >> 1;             // 0..255, one A row per thread
    const int acb  = (t & 1) * 2;        // A chunk base (k-octets 0,1 or 2,3)
    const int bn2  = (t & 127) * 2;      // 0..254, two B cols per thread
    const int bko  = (t >> 7) * 8;       // k-octet row block
    const int bcc  = t >> 7;             // B chunk = k-octet index (0..3)

    f32x4 acc[8][4];
    #pragma unroll
    for (int i = 0; i < 8; ++i)
        #pragma unroll
        for (int j = 0; j < 4; ++j)
            #pragma unroll
            for (int r = 0; r < 4; ++r)
                acc[i][j][r] = 0.0f;

    // ---- running global pointers ----
    const float* aP = A + (size_t)(m0 + arow) * KDIM + (t & 1) * 16;
    const int*   qP = Q + (size_t)bko * NDIM + n0 + bn2;

    // ---- prefetch register bank (consumed at kt, reissued at kt) ----
    float4 ra0, ra1, ra2, ra3;
    int2   rq[8];
    float2 sc;
    int2   zp;

    auto LOAD = [&](int kt) {
        ra0 = ((const float4*)aP)[0];
        ra1 = ((const float4*)aP)[1];
        ra2 = ((const float4*)aP)[2];
        ra3 = ((const float4*)aP)[3];
        const int* q = qP;
        #pragma unroll
        for (int j = 0; j < 8; ++j) {
            rq[j] = *(const int2*)q;
            q += NDIM;
        }
        if ((kt & 3) == 0) {            // params for group kt>>2; prior
            const int g = kt >> 2;      // group's last STORE already done
            sc = *(const float2*)(S + (size_t)g * NDIM + n0 + bn2);
            zp = *(const int2*)  (Z + (size_t)g * NDIM + n0 + bn2);
        }
        aP += 32;
        qP += (size_t)32 * NDIM;
    };

    auto STORE_A = [&](int buf) {       // waits (counted) on ra regs only
        bf16x8 v0, v1;
        v0[0] = (__bf16)ra0.x; v0[1] = (__bf16)ra0.y;
        v0[2] = (__bf16)ra0.z; v0[3] = (__bf16)ra0.w;
        v0[4] = (__bf16)ra1.x; v0[5] = (__bf16)ra1.y;
        v0[6] = (__bf16)ra1.z; v0[7] = (__bf16)ra1.w;
        v1[0] = (__bf16)ra2.x; v1[1] = (__bf16)ra2.y;
        v1[2] = (__bf16)ra2.z; v1[3] = (__bf16)ra2.w;
        v1[4] = (__bf16)ra3.x; v1[5] = (__bf16)ra3.y;
        v1[6] = (__bf16)ra3.z; v1[7] = (__bf16)ra3.w;
        *(bf16x8*)((char*)sA[buf] + SW(arow, acb))     = v0;
        *(bf16x8*)((char*)sA[buf] + SW(arow, acb + 1)) = v1;
    };

    auto STORE_B = [&](int buf) {       // dequant + write, waits on rq regs
        const float zs0 = -(float)zp.x * sc.x;
        const float zs1 = -(float)zp.y * sc.y;
        bf16x8 w0, w1;
        #pragma unroll
        for (int j = 0; j < 8; ++j) {
            w0[j] = (__bf16)((float)rq[j].x * sc.x + zs0);
            w1[j] = (__bf16)((float)rq[j].y * sc.y + zs1);
        }
        *(bf16x8*)((char*)sB[buf] + SW(bn2,     bcc)) = w0;
        *(bf16x8*)((char*)sB[buf] + SW(bn2 + 1, bcc)) = w1;
    };

    auto PH_WAIT = [&]() {   // phase turn: lock waves, drain own LDS ops
        __builtin_amdgcn_sched_barrier(0);
        __builtin_amdgcn_s_barrier();
        asm volatile("s_waitcnt lgkmcnt(0)" ::: "memory");
        __builtin_amdgcn_sched_barrier(0);   // rule #18: keep MFMA below wait
    };
    auto PH_END = [&]() {    // close the MFMA cluster
        __builtin_amdgcn_sched_barrier(0);
        __builtin_amdgcn_s_barrier();
    };

    #define MM8(I0, J0)                                                     \
        do {                                                                \
            __builtin_amdgcn_s_setprio(1);                                  \
            _Pragma("unroll")                                               \
            for (int i_ = 0; i_ < 4; ++i_)                                  \
                _Pragma("unroll")                                           \
                for (int j_ = 0; j_ < 2; ++j_)                              \
                    acc[(I0) + i_][(J0) + j_] =                             \
                        __builtin_amdgcn_mfma_f32_16x16x32_bf16(            \
                            aF[(I0) + i_], bF[(J0) + j_],                   \
                            acc[(I0) + i_][(J0) + j_], 0, 0, 0);            \
            __builtin_amdgcn_s_setprio(0);                                  \
        } while (0)

    // one k-step: compute tile from buf, stage tile kstage -> buf^1,
    // issue loads for tile kload. All conditions wave-uniform.
    auto STEP = [&](int buf, int kstage, int kload) {
        bf16x8 aF[8], bF[4];
        const char* bA = (const char*)sA[buf];
        const char* bB = (const char*)sB[buf];

        // ---- P0: quadrant (i 0..3, j 0..1) reads ----
        #pragma unroll
        for (int i = 0; i < 4; ++i)
            aF[i] = *(const bf16x8*)(bA + SW(wm + 16 * i + fr, fq));
        #pragma unroll
        for (int j = 0; j < 2; ++j)
            bF[j] = *(const bf16x8*)(bB + SW(wn + 16 * j + fr, fq));
        PH_WAIT();
        MM8(0, 0);
        PH_END();

        // ---- P1: remaining reads + stage A ----
        #pragma unroll
        for (int i = 4; i < 8; ++i)
            aF[i] = *(const bf16x8*)(bA + SW(wm + 16 * i + fr, fq));
        #pragma unroll
        for (int j = 2; j < 4; ++j)
            bF[j] = *(const bf16x8*)(bB + SW(wn + 16 * j + fr, fq));
        if (kstage < NT) STORE_A(buf ^ 1);
        PH_WAIT();
        MM8(0, 2);
        PH_END();

        // ---- P2: stage B (dequant) + issue next tile's global loads ----
        if (kstage < NT) STORE_B(buf ^ 1);
        if (kload < NT) LOAD(kload);
        PH_WAIT();
        MM8(4, 0);
        PH_END();

        // ---- P3: last quadrant (frags ready since P1), end-of-step bar ----
        MM8(4, 2);
        __builtin_amdgcn_sched_barrier(0);
        __builtin_amdgcn_s_barrier();
    };

    // ---- prologue: buf0 = tile0; tile1's loads left IN FLIGHT ----
    LOAD(0);
    STORE_A(0);
    STORE_B(0);
    LOAD(1);
    asm volatile("s_waitcnt lgkmcnt(0)" ::: "memory");
    __builtin_amdgcn_s_barrier();

    // ---- main loop: 2 k-steps per iter, static buffer indices ----
    for (int kt = 0; kt < NT; kt += 2) {
        STEP(0, kt + 1, kt + 2);
        STEP(1, kt + 2, kt + 3);
    }

    #undef MM8

    // ---- epilogue: C/D col = lane&15, row = (lane>>4)*4 + r ----
    float bj[4];
    #pragma unroll
    for (int j = 0; j < 4; ++j)
        bj[j] = bias[n0 + wn + 16 * j + fr];

    #pragma unroll
    for (int i = 0; i < 8; ++i) {
        #pragma unroll
        for (int r = 0; r < 4; ++r) {
            const int m = m0 + wm + 16 * i + fq * 4 + r;
            float* op = out + (size_t)m * NDIM + n0 + wn + fr;
            #pragma unroll
            for (int j = 0; j < 4; ++j)
                op[16 * j] = acc[i][j][r] + bj[j];
        }
    }
}

extern "C" void kernel_launch(void* const* d_in, const int* in_sizes, int n_in,
                              void* d_out, int out_size, void* d_ws, size_t ws_size,
                              hipStream_t stream) {
    const float* A    = (const float*)d_in[0];
    const int*   Q    = (const int*)d_in[1];
    const float* S    = (const float*)d_in[2];
    const int*   Z    = (const int*)d_in[3];
    const float* bias = (const float*)d_in[4];
    float* out = (float*)d_out;

    const int grid = (MDIM / 256) * (NDIM / 256);   // 688 blocks
    int4_gemm_mfma<<<dim3(grid), dim3(512), 0, stream>>>(A, Q, S, Z, bias, out);
}

// Round 8
// 954.253 us; speedup vs baseline: 1.0289x; 1.0289x over previous
//
#include <hip/hip_runtime.h>
#include <hip/hip_bf16.h>
#include <stdint.h>

#define MDIM 4096
#define KDIM 4096
#define NDIM 11008
#define NT   (KDIM / 32)   // 128 k-steps

typedef __bf16 bf16x8 __attribute__((ext_vector_type(8)));
typedef float  f32x4  __attribute__((ext_vector_type(4)));

// 256x256 tile, BK=32, 512 threads = 8 waves (2m x 4n); each wave owns
// 128x64 via 8x4 mfma_f32_16x16x32_bf16 fragments (32 MFMA per k-step).
// Round-8 = round-7 resubmission (round-7 died to an infra flake, same as
// round 4 -> round 5). Structure = round-5 pipeline (best measured: 695 us
// steady) + two edits:
//  1. bn-fastest XCD mapping: XCD x owns wg [86x,86x+86), bm=wg/43,
//     bn=wg%43 -> one A row-strip (4MB) per XCD at a time (L2-resident),
//     all XCDs sweep the same bn range together (Q shared via LLC).
//     Round-5's bm-fastest walk re-fetched A ~9x (FETCH 1.05GB).
//  2. MFMA cluster issued BEFORE the staging STORE in each half-step:
//     frag reads -> MFMA (counted lgkm waits) -> STORE (dequant VALU runs
//     under co-resident wave's MFMA tail) -> LOAD -> barrier.
// Pipeline invariants (round-5, verified passing): global loads issued at
// step kt are consumed at kt+1 (full-step latency cover, single reg bank);
// per-step barrier is raw s_barrier + lgkmcnt(0) only -- the 12 in-flight
// global loads cross the barrier (no vmcnt drain). 4-phase split was tried
// (round 6) and REGRESSED: dequant VALU inside phases makes extra barriers
// convoy overhead. Do not re-add phase barriers while dequant is in-loop.
// LDS (both sA, sB): rows of 32 bf16 (4x 16B chunks) in 2-row 128B windows,
// slot(row,c) = ((row&1)*4 + c) ^ ((row>>1)&7)  -- measured conflict-free
// (rounds 3-6: SQ_LDS_BANK_CONFLICT == 0).
// Fragment contracts (harness-verified):
//   A operand: lane(fr,fq) holds A[m=16i+fr][k=fq*8+e]
//   B operand: lane(fr,fq) holds B[k=fq*8+e][n=16j+fr]
//   C/D:       col = lane&15, row = (lane>>4)*4 + r
__global__ __launch_bounds__(512) void int4_gemm_mfma(
    const float* __restrict__ A, const int* __restrict__ Q,
    const float* __restrict__ S, const int* __restrict__ Z,
    const float* __restrict__ bias, float* __restrict__ out)
{
    __shared__ __bf16 sA[2][256 * 32];   // 2 x 16KB
    __shared__ __bf16 sB[2][256 * 32];   // 2 x 16KB  ([n][k])

    auto SW = [](int row, int c) -> int {
        return ((row >> 1) << 7) + (((((row & 1) << 2) | c) ^ ((row >> 1) & 7)) << 4);
    };

    // ---- XCD-chunked mapping, bn fastest (A strip L2-resident per XCD) ----
    const int nbn = NDIM / 256;                      // 43
    const int nwg = (MDIM / 256) * (NDIM / 256);     // 688 (divisible by 8)
    const int xcd = blockIdx.x & 7;
    const int wgl = xcd * (nwg >> 3) + (blockIdx.x >> 3);   // 0..687
    const int bm  = (unsigned)wgl / (unsigned)nbn;          // magic-mul div
    const int bn  = wgl - bm * nbn;
    const int m0 = bm * 256, n0 = bn * 256;

    const int t    = threadIdx.x;
    const int lane = t & 63;
    const int wave = t >> 6;
    const int wm   = (wave >> 2) * 128;  // wave tile: 128m x 64n
    const int wn   = (wave & 3) * 64;
    const int fr   = lane & 15;
    const int fq   = lane >> 4;          // k-octet

    // ---- staging maps ----
    const int arow = t >> 1;             // 0..255, one A row per thread
    const int acb  = (t & 1) * 2;        // A chunk base (k-octets 0,1 or 2,3)
    const int bn2  = (t & 127) * 2;      // 0..254, two B cols per thread
    const int bko  = (t >> 7) * 8;       // k-octet row block
    const int bcc  = t >> 7;             // B chunk = k-octet index (0..3)

    f32x4 acc[8][4];
    #pragma unroll
    for (int i = 0; i < 8; ++i)
        #pragma unroll
        for (int j = 0; j < 4; ++j)
            #pragma unroll
            for (int r = 0; r < 4; ++r)
                acc[i][j][r] = 0.0f;

    // ---- running global pointers ----
    const float* aP = A + (size_t)(m0 + arow) * KDIM + (t & 1) * 16;
    const int*   qP = Q + (size_t)bko * NDIM + n0 + bn2;

    // ---- prefetch register bank (consumed at kt, reissued at kt) ----
    float4 ra0, ra1, ra2, ra3;
    int2   rq[8];
    float2 sc;
    int2   zp;

    auto LOAD = [&](int kt) {
        ra0 = ((const float4*)aP)[0];
        ra1 = ((const float4*)aP)[1];
        ra2 = ((const float4*)aP)[2];
        ra3 = ((const float4*)aP)[3];
        const int* q = qP;
        #pragma unroll
        for (int j = 0; j < 8; ++j) {
            rq[j] = *(const int2*)q;
            q += NDIM;
        }
        if ((kt & 3) == 0) {            // params for group kt>>2; prior
            const int g = kt >> 2;      // group's last STORE already done
            sc = *(const float2*)(S + (size_t)g * NDIM + n0 + bn2);
            zp = *(const int2*)  (Z + (size_t)g * NDIM + n0 + bn2);
        }
        aP += 32;
        qP += (size_t)32 * NDIM;
    };

    auto STORE = [&](int buf) {
        bf16x8 v0, v1;
        v0[0] = (__bf16)ra0.x; v0[1] = (__bf16)ra0.y;
        v0[2] = (__bf16)ra0.z; v0[3] = (__bf16)ra0.w;
        v0[4] = (__bf16)ra1.x; v0[5] = (__bf16)ra1.y;
        v0[6] = (__bf16)ra1.z; v0[7] = (__bf16)ra1.w;
        v1[0] = (__bf16)ra2.x; v1[1] = (__bf16)ra2.y;
        v1[2] = (__bf16)ra2.z; v1[3] = (__bf16)ra2.w;
        v1[4] = (__bf16)ra3.x; v1[5] = (__bf16)ra3.y;
        v1[6] = (__bf16)ra3.z; v1[7] = (__bf16)ra3.w;
        *(bf16x8*)((char*)sA[buf] + SW(arow, acb))     = v0;
        *(bf16x8*)((char*)sA[buf] + SW(arow, acb + 1)) = v1;

        const float zs0 = -(float)zp.x * sc.x;
        const float zs1 = -(float)zp.y * sc.y;
        bf16x8 w0, w1;
        #pragma unroll
        for (int j = 0; j < 8; ++j) {
            w0[j] = (__bf16)((float)rq[j].x * sc.x + zs0);
            w1[j] = (__bf16)((float)rq[j].y * sc.y + zs1);
        }
        *(bf16x8*)((char*)sB[buf] + SW(bn2,     bcc)) = w0;
        *(bf16x8*)((char*)sB[buf] + SW(bn2 + 1, bcc)) = w1;
    };

    auto FRAGS = [&](int buf, bf16x8 (&aF)[8], bf16x8 (&bF)[4]) {
        #pragma unroll
        for (int i = 0; i < 8; ++i)
            aF[i] = *(const bf16x8*)((char*)sA[buf] + SW(wm + 16 * i + fr, fq));
        #pragma unroll
        for (int j = 0; j < 4; ++j)
            bF[j] = *(const bf16x8*)((char*)sB[buf] + SW(wn + 16 * j + fr, fq));
    };

    auto MFMAS = [&](bf16x8 (&aF)[8], bf16x8 (&bF)[4]) {
        __builtin_amdgcn_s_setprio(1);
        #pragma unroll
        for (int i = 0; i < 8; ++i)
            #pragma unroll
            for (int j = 0; j < 4; ++j)
                acc[i][j] = __builtin_amdgcn_mfma_f32_16x16x32_bf16(
                                aF[i], bF[j], acc[i][j], 0, 0, 0);
        __builtin_amdgcn_s_setprio(0);
    };

    auto BAR = [&]() {   // release own LDS ops, raw barrier; globals fly over
        asm volatile("s_waitcnt lgkmcnt(0)" ::: "memory");
        __builtin_amdgcn_s_barrier();
    };

    // ---- prologue: buf0 = tile0; tile1's loads left IN FLIGHT ----
    LOAD(0);
    STORE(0);                       // compiler inserts exact vmcnt waits
    LOAD(1);
    BAR();

    // ---- main loop, 2x unrolled: one raw barrier per k-step ----
    for (int kt = 0; kt < NT; kt += 2) {
        {   // half A: compute buf0 (tile kt); stage tile kt+1 -> buf1
            bf16x8 aF[8], bF[4];
            FRAGS(0, aF, bF);
            MFMAS(aF, bF);                     // fire matrix pipe first
            STORE(1);                          // regs = tile kt+1 (issued kt-1)
            if (kt + 2 < NT) LOAD(kt + 2);     // reissue bank for tile kt+2
            BAR();
        }
        {   // half B: compute buf1 (tile kt+1); stage tile kt+2 -> buf0
            bf16x8 aF[8], bF[4];
            FRAGS(1, aF, bF);
            MFMAS(aF, bF);
            if (kt + 2 < NT) STORE(0);         // regs = tile kt+2
            if (kt + 3 < NT) LOAD(kt + 3);
            BAR();
        }
    }

    // ---- epilogue: C/D col = lane&15, row = (lane>>4)*4 + r ----
    float bj[4];
    #pragma unroll
    for (int j = 0; j < 4; ++j)
        bj[j] = bias[n0 + wn + 16 * j + fr];

    #pragma unroll
    for (int i = 0; i < 8; ++i) {
        #pragma unroll
        for (int r = 0; r < 4; ++r) {
            const int m = m0 + wm + 16 * i + fq * 4 + r;
            float* op = out + (size_t)m * NDIM + n0 + wn + fr;
            #pragma unroll
            for (int j = 0; j < 4; ++j)
                op[16 * j] = acc[i][j][r] + bj[j];
        }
    }
}

extern "C" void kernel_launch(void* const* d_in, const int* in_sizes, int n_in,
                              void* d_out, int out_size, void* d_ws, size_t ws_size,
                              hipStream_t stream) {
    const float* A    = (const float*)d_in[0];
    const int*   Q    = (const int*)d_in[1];
    const float* S    = (const float*)d_in[2];
    const int*   Z    = (const int*)d_in[3];
    const float* bias = (const float*)d_in[4];
    float* out = (float*)d_out;

    const int grid = (MDIM / 256) * (NDIM / 256);   // 688 blocks
    int4_gemm_mfma<<<dim3(grid), dim3(512), 0, stream>>>(A, Q, S, Z, bias, out);
}

// Round 9
// 878.969 us; speedup vs baseline: 1.1170x; 1.0857x over previous
//
#include <hip/hip_runtime.h>
#include <hip/hip_bf16.h>
#include <stdint.h>

#define MDIM 4096
#define KDIM 4096
#define NDIM 11008
#define NT   (KDIM / 32)   // 128 k-steps

typedef __bf16 bf16x8 __attribute__((ext_vector_type(8)));
typedef float  f32x4  __attribute__((ext_vector_type(4)));

typedef __attribute__((address_space(1))) const void gv_t;   // global
typedef __attribute__((address_space(3))) void       lv_t;   // LDS

// 256x256 tile, BK=32, 512 threads = 8 waves (4m x 2n); each wave owns
// 64m x 128n via 4x8 mfma_f32_16x16x32_bf16 fragments (32 MFMA/k-step).
// Round-9:
//  - Mapping reverted to round-5 bm-fastest XCD walk (measured best:
//    FETCH 1.05GB, 695us; round-8's bn-fastest REGRESSED to 1.50GB/765us).
//  - A is staged fp32 straight to LDS via global_load_lds (async DMA):
//    no reg bank, no staging VALU, 2-step-deep prefetch into a 3-buffer.
//    Swizzle via pre-swizzled per-lane GLOBAL source + linear LDS dest
//    (m104/m173 semantics): lane l of issue i stages row 32w+8i+(l>>3),
//    k-chunk (l&7)^(l>>3), landing at linear dst+l*16 == swizzled layout
//    chunk' = chunk ^ (row&7). Frag reads are 2x ds_read_b128 + cvt,
//    64 distinct 16B chunks per instruction (bank-uniform floor).
//  - Counted-vmcnt barrier (T4): every steady step issues exactly 14 VMEM
//    (Q 8 + S/Z 2 + A 4). End-of-step = wait vmcnt(14) lgkm(0) THEN
//    s_barrier: guarantees A(kt+1) landed chip-visibly, keeps the newest
//    14 loads in flight across the barrier. Never drains to 0 mid-loop.
//  - B path unchanged (reg-staged dequant, verified window swizzle,
//    SQ_LDS_BANK_CONFLICT == 0 in rounds 3-8).
// Fragment contracts (harness-verified):
//   A operand: lane(fr,fq) holds A[m=16i+fr][k=fq*8+e]
//   B operand: lane(fr,fq) holds B[k=fq*8+e][n=16j+fr]
//   C/D:       col = lane&15, row = (lane>>4)*4 + r
__global__ __launch_bounds__(512) void int4_gemm_mfma(
    const float* __restrict__ A, const int* __restrict__ Q,
    const float* __restrict__ S, const int* __restrict__ Z,
    const float* __restrict__ bias, float* __restrict__ out)
{
    __shared__ float  sAf[3][256 * 32];   // 3 x 32KB fp32, src-swizzled
    __shared__ __bf16 sB [2][256 * 32];   // 2 x 16KB bf16 [n][k]

    // B swizzle: rows of 32 bf16 (64B) in 2-row 128B windows
    auto SW = [](int row, int c) -> int {
        return ((row >> 1) << 7) + (((((row & 1) << 2) | c) ^ ((row >> 1) & 7)) << 4);
    };

    // ---- XCD-chunked mapping, bm fastest (round-5, measured best) ----
    const int nbm = MDIM / 256;                      // 16
    const int nwg = (MDIM / 256) * (NDIM / 256);     // 688 (divisible by 8)
    const int xcd = blockIdx.x & 7;
    const int wg  = xcd * (nwg >> 3) + (blockIdx.x >> 3);
    const int bm  = wg % nbm;
    const int bn  = wg / nbm;
    const int m0 = bm * 256, n0 = bn * 256;

    const int t    = threadIdx.x;
    const int lane = t & 63;
    const int wave = t >> 6;
    const int wm   = (wave & 3) * 64;    // wave tile: 64m x 128n
    const int wn2  = (wave >> 2) * 128;
    const int fr   = lane & 15;
    const int fq   = lane >> 4;          // k-octet
    const int f7   = fr & 7;

    // ---- B staging maps (unchanged) ----
    const int bn2  = (t & 127) * 2;      // two B cols per thread
    const int bko  = (t >> 7) * 8;       // k-octet row block
    const int bcc  = t >> 7;             // B chunk = k-octet index

    f32x4 acc[4][8];
    #pragma unroll
    for (int i = 0; i < 4; ++i)
        #pragma unroll
        for (int j = 0; j < 8; ++j)
            #pragma unroll
            for (int r = 0; r < 4; ++r)
                acc[i][j][r] = 0.0f;

    // ---- A DMA source (per-lane, pre-swizzled), advances 32 floats/tile ----
    const float* aGP = A + (size_t)(m0 + 32 * wave + (lane >> 3)) * KDIM
                         + (((lane & 7) ^ (lane >> 3)) << 2);
    // ---- Q running pointer ----
    const int* qP = Q + (size_t)bko * NDIM + n0 + bn2;

    // ---- Q prefetch bank (consumed at kt, reissued at kt) ----
    int2   rq[8];
    float2 sc;
    int2   zp;

    auto ISSUE_A = [&](int wbuf) {       // 4 VMEM ops, async -> sAf[wbuf]
        lv_t* dst = (lv_t*)&sAf[wbuf][wave * 1024];   // wave-uniform base
        #pragma unroll
        for (int i = 0; i < 4; ++i)
            __builtin_amdgcn_global_load_lds(
                (gv_t*)(aGP + (size_t)i * 8 * KDIM),
                (lv_t*)((char*)dst + i * 1024), 16, 0, 0);
        aGP += 32;
    };

    auto LOAD_Q = [&](int tile) {        // 10 VMEM ops (8 Q + S + Z)
        const int* q = qP;
        #pragma unroll
        for (int j = 0; j < 8; ++j) {
            rq[j] = *(const int2*)q;
            q += NDIM;
        }
        const int g = tile >> 2;
        sc = *(const float2*)(S + (size_t)g * NDIM + n0 + bn2);
        zp = *(const int2*)  (Z + (size_t)g * NDIM + n0 + bn2);
        qP += (size_t)32 * NDIM;
    };

    auto STORE_B = [&](int buf) {        // dequant + 2x ds_write_b128
        const float zs0 = -(float)zp.x * sc.x;
        const float zs1 = -(float)zp.y * sc.y;
        bf16x8 w0, w1;
        #pragma unroll
        for (int j = 0; j < 8; ++j) {
            w0[j] = (__bf16)((float)rq[j].x * sc.x + zs0);
            w1[j] = (__bf16)((float)rq[j].y * sc.y + zs1);
        }
        *(bf16x8*)((char*)sB[buf] + SW(bn2,     bcc)) = w0;
        *(bf16x8*)((char*)sB[buf] + SW(bn2 + 1, bcc)) = w1;
    };

    // ---- prologue: tiles 0,1 of A in flight/landed; B(0) staged ----
    LOAD_Q(0);          // 10
    ISSUE_A(0);         // 4  -> sAf[0]
    ISSUE_A(1);         // 4  -> sAf[1]
    STORE_B(0);         // consumes Q(0); compiler-counted vmcnt wait
    LOAD_Q(1);          // 10
    asm volatile("s_waitcnt vmcnt(14) lgkmcnt(0)" ::: "memory");  // A(0) done
    __builtin_amdgcn_s_barrier();

    // ---- main loop: one counted-vmcnt barrier per k-step ----
    int ab = 0;                                   // A read buf = kt % 3
    for (int kt = 0; kt < NT; ++kt) {
        const char* abuf = (const char*)sAf[ab];
        const char* bbuf = (const char*)sB[kt & 1];

        // fragments: A fp32 (2x b128 + cvt), B bf16 (1x b128)
        bf16x8 aF[4], bF[8];
        #pragma unroll
        for (int i = 0; i < 4; ++i) {
            const char* rp = abuf + (size_t)(wm + 16 * i + fr) * 128;
            f32x4 u0 = *(const f32x4*)(rp + ((( 2 * fq    ) ^ f7) << 4));
            f32x4 u1 = *(const f32x4*)(rp + (((2 * fq + 1) ^ f7) << 4));
            bf16x8 v;
            v[0] = (__bf16)u0[0]; v[1] = (__bf16)u0[1];
            v[2] = (__bf16)u0[2]; v[3] = (__bf16)u0[3];
            v[4] = (__bf16)u1[0]; v[5] = (__bf16)u1[1];
            v[6] = (__bf16)u1[2]; v[7] = (__bf16)u1[3];
            aF[i] = v;
        }
        #pragma unroll
        for (int j = 0; j < 8; ++j)
            bF[j] = *(const bf16x8*)(bbuf + SW(wn2 + 16 * j + fr, fq));

        if (kt < NT - 1) STORE_B((kt + 1) & 1);   // stage B(kt+1)
        if (kt < NT - 2) {                        // issue tile kt+2 (14 ops)
            LOAD_Q(kt + 2);
            int wb = ab + 2; if (wb >= 3) wb -= 3;
            ISSUE_A(wb);
        }

        __builtin_amdgcn_s_setprio(1);
        #pragma unroll
        for (int i = 0; i < 4; ++i)
            #pragma unroll
            for (int j = 0; j < 8; ++j)
                acc[i][j] = __builtin_amdgcn_mfma_f32_16x16x32_bf16(
                                aF[i], bF[j], acc[i][j], 0, 0, 0);
        __builtin_amdgcn_s_setprio(0);

        // end-of-step: wait THEN barrier. Steady: newest 14 (Q+SZ+A of
        // tile kt+2) stay in flight; everything older (incl. A(kt+1) DMA
        // writes) is drained and made cross-wave visible by the barrier.
        if (kt < NT - 2) {
            asm volatile("s_waitcnt vmcnt(14) lgkmcnt(0)" ::: "memory");
            __builtin_amdgcn_s_barrier();
        } else if (kt == NT - 2) {
            asm volatile("s_waitcnt vmcnt(0) lgkmcnt(0)" ::: "memory");
            __builtin_amdgcn_s_barrier();
        }
        ab = (ab == 2) ? 0 : ab + 1;
    }

    // ---- epilogue: C/D col = lane&15, row = (lane>>4)*4 + r ----
    float bj[8];
    #pragma unroll
    for (int j = 0; j < 8; ++j)
        bj[j] = bias[n0 + wn2 + 16 * j + fr];

    #pragma unroll
    for (int i = 0; i < 4; ++i) {
        #pragma unroll
        for (int r = 0; r < 4; ++r) {
            const int m = m0 + wm + 16 * i + fq * 4 + r;
            float* op = out + (size_t)m * NDIM + n0 + wn2 + fr;
            #pragma unroll
            for (int j = 0; j < 8; ++j)
                op[16 * j] = acc[i][j][r] + bj[j];
        }
    }
}

extern "C" void kernel_launch(void* const* d_in, const int* in_sizes, int n_in,
                              void* d_out, int out_size, void* d_ws, size_t ws_size,
                              hipStream_t stream) {
    const float* A    = (const float*)d_in[0];
    const int*   Q    = (const int*)d_in[1];
    const float* S    = (const float*)d_in[2];
    const int*   Z    = (const int*)d_in[3];
    const float* bias = (const float*)d_in[4];
    float* out = (float*)d_out;

    const int grid = (MDIM / 256) * (NDIM / 256);   // 688 blocks
    int4_gemm_mfma<<<dim3(grid), dim3(512), 0, stream>>>(A, Q, S, Z, bias, out);
}